// Round 7
// baseline (307.343 us; speedup 1.0000x reference)
//
#include <hip/hip_runtime.h>
#include <math.h>

#define B_N 64
#define C_N 512
#define M_N 1024
#define K_W 2048  // W row: [H bf16 (1024) | X'=g*(h+pe) bf16 (1024)]
#define BK 64
#define NT 32     // K-tiles of 64

typedef __attribute__((ext_vector_type(8))) short bf16x8;
typedef __attribute__((ext_vector_type(4))) float f32x4;

__device__ __forceinline__ unsigned short f2b(float f) {
  unsigned int x = __builtin_bit_cast(unsigned int, f);
  unsigned int lsb = (x >> 16) & 1u;
  x += 0x7fffu + lsb;
  return (unsigned short)(x >> 16);
}

typedef __attribute__((address_space(1))) const unsigned int gas_uint;
typedef __attribute__((address_space(3))) unsigned int las_uint;
__device__ __forceinline__ void async_ld(const void* g, const void* l) {
  __builtin_amdgcn_global_load_lds((gas_uint*)(uintptr_t)g,
                                   (las_uint*)(unsigned int)(uintptr_t)l, 16, 0, 0);
}

// ---------- positional embedding fp32 [C][M] + fused per-row sums ----------
__global__ void k_pe(float* __restrict__ pe, float* __restrict__ pesum) {
  int c = blockIdx.x, m = threadIdx.x;
  float freq = expf((float)(c & ~1) * (-9.210340371976184f / 512.0f));
  float ang = (float)m * freq;
  float v = (c & 1) ? cosf(ang) : sinf(ang);
  pe[c * M_N + m] = v;
  float s = v;
  for (int off = 32; off; off >>= 1) s += __shfl_down(s, off);
  __shared__ float ws[16];
  if ((m & 63) == 0) ws[m >> 6] = s;
  __syncthreads();
  if (m < 16) {
    float t = ws[m];
    for (int off = 8; off; off >>= 1) t += __shfl_down(t, off);
    if (m == 0) pesum[c] = t;
  }
}

// ---------- pass 1: fp32 row sums, atomic-free (block owns exactly 2 rows) --
__global__ void k_rs(const float* __restrict__ src, float* __restrict__ rb) {
  __shared__ float ws[4];
  int t = threadIdx.x;
  size_t e = ((size_t)blockIdx.x * 256 + t) * 8;
  const float4* s4 = (const float4*)(src + e);
  float4 v0 = s4[0], v1 = s4[1];
  float s = v0.x + v0.y + v0.z + v0.w + v1.x + v1.y + v1.z + v1.w;
  for (int off = 32; off; off >>= 1) s += __shfl_down(s, off);
  if ((t & 63) == 0) ws[t >> 6] = s;
  __syncthreads();
  if (t == 0) rb[blockIdx.x * 2] = ws[0] + ws[1];
  if (t == 128) rb[blockIdx.x * 2 + 1] = ws[2] + ws[3];
}

// ---------- gate (fp32 exact): outputs u = g*(rb+pesum), rb copy, g ----------
__global__ void k_gate(const float* __restrict__ wp, const float* __restrict__ bp,
                       const float* __restrict__ rb0, const float* __restrict__ pesum,
                       float* __restrict__ u, float* __restrict__ rbF,
                       float* __restrict__ gateF) {
  int idx = blockIdx.x * 256 + threadIdx.x;
  int b = idx >> 9, c = idx & (C_N - 1);
  float rbv = rb0[idx];
  float rx = rbv + pesum[c];
  float acc = 0.f;
  for (int k = 0; k < 5; ++k) {
    int cc = c + k - 2;
    if (cc < 0 || cc >= C_N) continue;
    float y = (rb0[b * C_N + cc] + pesum[cc]) * (1.0f / 1024.0f);
    acc += y * wp[c * 5 + k];
  }
  float g = 1.0f / (1.0f + expf(-(acc + bp[c])));
  gateF[idx] = g;
  u[idx] = g * rx;
  rbF[idx] = rbv;
}

// ---------- pass 2: IN-PLACE fp32 row -> [H bf16 | X' bf16] -----------------
__global__ void k_x(const float* __restrict__ src, unsigned short* __restrict__ Wd,
                    const float* __restrict__ pe, const float* __restrict__ gateF) {
  int row = blockIdx.x;
  int c = row & (C_N - 1), t = threadIdx.x;
  const float* rp = src + (size_t)row * M_N;
  float4 h4 = ((const float4*)rp)[t];
  float4 p4 = ((const float4*)(pe + (size_t)c * M_N))[t];
  float g = gateF[row];
  union { uint2 v; unsigned short us[4]; } H, X;
  H.us[0] = f2b(h4.x); H.us[1] = f2b(h4.y); H.us[2] = f2b(h4.z); H.us[3] = f2b(h4.w);
  X.us[0] = f2b(g * (h4.x + p4.x)); X.us[1] = f2b(g * (h4.y + p4.y));
  X.us[2] = f2b(g * (h4.z + p4.z)); X.us[3] = f2b(g * (h4.w + p4.w));
  __syncthreads();
  unsigned short* wr = Wd + (size_t)row * K_W;
  ((uint2*)wr)[t] = H.v;
  ((uint2*)(wr + M_N))[t] = X.v;
}

// ---------- cov: 256x256 triangle SYRK, 8-phase counted-vmcnt schedule ------
// out = (W W^T)/M - (u u^T + rb rb^T)/M^2 (+1e-8 I).
// 8 waves (2Mx4N), wave-tile 128x64, BK=64, LDS 2 dbuf x (A,B) 256x64 = 128KiB.
// Per phase: {ds-read quadrant (+all B on q0) || stage 1 half-tile -> barrier
// -> lgkm(0) -> setprio+16 MFMA -> [vmcnt(4) at p4/p8] -> barrier}.
// Stage-safety: a buf half is overwritten only >=1 closing-barrier after its
// last ds_read phase; readiness certified by vmcnt-before-barrier at p4/p8.
// LDS swizzle: chunk' = chunk ^ (row&7), applied to BOTH the pre-swizzled
// global stage source and the ds_read address (rule #21).
__device__ __forceinline__ bf16x8 MF(bf16x8 a, bf16x8 b, f32x4& c) {
  c = __builtin_amdgcn_mfma_f32_16x16x32_bf16(a, b, c, 0, 0, 0);
  return a;
}

template <int QUAD, bool RDB, bool STG, int VMN>
__device__ __forceinline__ void phase(
    const short* lA, const short* lB, const unsigned short* ssrc, short* sdst,
    int wm, int wn, int fr, int chA0, int chA1,
    bf16x8 (&bfr)[4][2], f32x4 (&acc)[8][4]) {
  bf16x8 af[2][2];
  int r0 = (wm * 128 + QUAD * 32 + fr) * BK;
  af[0][0] = *(const bf16x8*)&lA[r0 + chA0 * 8];
  af[0][1] = *(const bf16x8*)&lA[r0 + chA1 * 8];
  af[1][0] = *(const bf16x8*)&lA[r0 + 16 * BK + chA0 * 8];
  af[1][1] = *(const bf16x8*)&lA[r0 + 16 * BK + chA1 * 8];
  if constexpr (RDB) {
#pragma unroll
    for (int j = 0; j < 4; j++) {
      int rb = (wn * 64 + j * 16 + fr) * BK;
      bfr[j][0] = *(const bf16x8*)&lB[rb + chA0 * 8];
      bfr[j][1] = *(const bf16x8*)&lB[rb + chA1 * 8];
    }
  }
  if constexpr (STG) {
    async_ld(ssrc, sdst);
    async_ld(ssrc + 8 * K_W, sdst + 8 * BK);
  }
  __builtin_amdgcn_s_barrier();
  __builtin_amdgcn_sched_barrier(0);
  asm volatile("s_waitcnt lgkmcnt(0)" ::: "memory");
  __builtin_amdgcn_sched_barrier(0);
  __builtin_amdgcn_s_setprio(1);
#pragma unroll
  for (int i2 = 0; i2 < 2; i2++)
#pragma unroll
    for (int j = 0; j < 4; j++) {
      acc[QUAD * 2 + i2][j] = __builtin_amdgcn_mfma_f32_16x16x32_bf16(
          af[i2][0], bfr[j][0], acc[QUAD * 2 + i2][j], 0, 0, 0);
      acc[QUAD * 2 + i2][j] = __builtin_amdgcn_mfma_f32_16x16x32_bf16(
          af[i2][1], bfr[j][1], acc[QUAD * 2 + i2][j], 0, 0, 0);
    }
  __builtin_amdgcn_s_setprio(0);
  if constexpr (VMN >= 0) {
    asm volatile("s_waitcnt vmcnt(%0)" ::"n"(VMN) : "memory");
    __builtin_amdgcn_sched_barrier(0);
  }
  __builtin_amdgcn_s_barrier();
  __builtin_amdgcn_sched_barrier(0);
}

__global__ __launch_bounds__(512, 2)
void k_cov8(const unsigned short* __restrict__ W, const float* __restrict__ aux,
            float* __restrict__ out, int b0, int bpx) {
  __shared__ short lds[2][2][256 * BK];  // [buf][op A=0/B=1] = 128 KiB
  int t = threadIdx.x, lane = t & 63, w = t >> 6;  // 8 waves
  int wm = w >> 2, wn = w & 3;
  int fr = lane & 15, kc = lane >> 4;
  int bid = blockIdx.x;
  int xcd = bid & 7, i3 = bid >> 3;
  int b = b0 + xcd * bpx + i3 / 3;
  int s = i3 % 3;
  int ti = (s + 1) >> 1, tj = s >> 1;  // (0,0),(1,0),(1,1)
  int cblk = ti * 256, dblk = tj * 256;

  // per-lane pre-swizzled stage sources: row = base + (lane>>3), chunk = (lane&7)^(lane>>3)
  int lr = lane >> 3, lc = lane & 7;
  const unsigned short* baseW = W + (size_t)b * (C_N * K_W);
  const unsigned short* srcA = baseW + (size_t)(cblk + lr) * K_W + (lc ^ lr) * 8;
  const unsigned short* srcB = baseW + (size_t)(dblk + lr) * K_W + (lc ^ lr) * 8;
  // fragment read chunk (swizzled): chunk = (ks*4+kc) ^ (fr&7)
  int chA0 = kc ^ (fr & 7);
  int chA1 = (4 + kc) ^ (fr & 7);
  int rw0 = w * 16;  // this wave's stage row block within a half

  f32x4 acc[8][4];
  const f32x4 z = {0.f, 0.f, 0.f, 0.f};
#pragma unroll
  for (int i = 0; i < 8; i++)
#pragma unroll
    for (int j = 0; j < 4; j++) acc[i][j] = z;
  bf16x8 bfr[4][2];

#define SRC_A(h, kt) (srcA + (size_t)((h)*128 + rw0) * K_W + (kt)*BK)
#define SRC_B(h, kt) (srcB + (size_t)((h)*128 + rw0) * K_W + (kt)*BK)
#define DST(buf, op, h) (&lds[buf][op][((h)*128 + rw0) * BK])
#define STG2(buf, op, h, srcp)            \
  {                                       \
    const unsigned short* _s = (srcp);    \
    short* _d = DST(buf, op, h);          \
    async_ld(_s, _d);                     \
    async_ld(_s + 8 * K_W, _d + 8 * BK);  \
  }

  // prologue: kt0=0 full (A0,A1,B0,B1 -> buf0), kt1=1 B halves -> buf1
  STG2(0, 0, 0, SRC_A(0, 0)); STG2(0, 0, 1, SRC_A(1, 0));
  STG2(0, 1, 0, SRC_B(0, 0)); STG2(0, 1, 1, SRC_B(1, 0));
  STG2(1, 1, 0, SRC_B(0, 1)); STG2(1, 1, 1, SRC_B(1, 1));
  asm volatile("s_waitcnt vmcnt(4)" ::: "memory");  // kt0 certified
  __builtin_amdgcn_sched_barrier(0);
  __builtin_amdgcn_s_barrier();
  __builtin_amdgcn_sched_barrier(0);

  // 15 generic iters (kt0=2n, kt1=2n+1), stages reach kt=31
  for (int n = 0; n < 15; ++n) {
    int kt0 = 2 * n, kt1 = 2 * n + 1;
    phase<0, true,  true, -1>(lds[0][0], lds[0][1], SRC_A(0, kt1), DST(1, 0, 0), wm, wn, fr, chA0, chA1, bfr, acc);
    phase<1, false, true, -1>(lds[0][0], lds[0][1], SRC_A(1, kt1), DST(1, 0, 1), wm, wn, fr, chA0, chA1, bfr, acc);
    phase<2, false, true, -1>(lds[0][0], lds[0][1], SRC_B(0, kt0 + 2), DST(0, 1, 0), wm, wn, fr, chA0, chA1, bfr, acc);
    phase<3, false, true,  4>(lds[0][0], lds[0][1], SRC_B(1, kt0 + 2), DST(0, 1, 1), wm, wn, fr, chA0, chA1, bfr, acc);
    phase<0, true,  true, -1>(lds[1][0], lds[1][1], SRC_A(0, kt0 + 2), DST(0, 0, 0), wm, wn, fr, chA0, chA1, bfr, acc);
    phase<1, false, true, -1>(lds[1][0], lds[1][1], SRC_A(1, kt0 + 2), DST(0, 0, 1), wm, wn, fr, chA0, chA1, bfr, acc);
    phase<2, false, true, -1>(lds[1][0], lds[1][1], SRC_B(0, kt1 + 2), DST(1, 1, 0), wm, wn, fr, chA0, chA1, bfr, acc);
    phase<3, false, true,  4>(lds[1][0], lds[1][1], SRC_B(1, kt1 + 2), DST(1, 1, 1), wm, wn, fr, chA0, chA1, bfr, acc);
  }
  // last iter (kt0=30, kt1=31): stage only kt31's A; vmcnt(0) certifies it
  phase<0, true,  true, -1>(lds[0][0], lds[0][1], SRC_A(0, 31), DST(1, 0, 0), wm, wn, fr, chA0, chA1, bfr, acc);
  phase<1, false, true, -1>(lds[0][0], lds[0][1], SRC_A(1, 31), DST(1, 0, 1), wm, wn, fr, chA0, chA1, bfr, acc);
  phase<2, false, false, -1>(lds[0][0], lds[0][1], nullptr, nullptr, wm, wn, fr, chA0, chA1, bfr, acc);
  phase<3, false, false,  0>(lds[0][0], lds[0][1], nullptr, nullptr, wm, wn, fr, chA0, chA1, bfr, acc);
  phase<0, true,  false, -1>(lds[1][0], lds[1][1], nullptr, nullptr, wm, wn, fr, chA0, chA1, bfr, acc);
  phase<1, false, false, -1>(lds[1][0], lds[1][1], nullptr, nullptr, wm, wn, fr, chA0, chA1, bfr, acc);
  phase<2, false, false, -1>(lds[1][0], lds[1][1], nullptr, nullptr, wm, wn, fr, chA0, chA1, bfr, acc);
  phase<3, false, false, -1>(lds[1][0], lds[1][1], nullptr, nullptr, wm, wn, fr, chA0, chA1, bfr, acc);

  const float invM = 1.0f / 1024.0f, invM2 = invM * invM;
  const float* ub = aux + (size_t)b * C_N;
  const float* rbb = aux + (size_t)B_N * C_N + (size_t)b * C_N;

  // direct write of the computed 256x256 tile
#pragma unroll
  for (int i = 0; i < 8; i++)
#pragma unroll
    for (int r = 0; r < 4; r++) {
      int c = cblk + wm * 128 + i * 16 + kc * 4 + r;
      float uc = ub[c], rbc = rbb[c];
#pragma unroll
      for (int j = 0; j < 4; j++) {
        int d = dblk + wn * 64 + j * 16 + fr;
        float v = acc[i][j][r] * invM - (uc * ub[d] + rbc * rbb[d]) * invM2;
        if (c == d) v += 1e-8f;
        out[((size_t)b * C_N + c) * C_N + d] = v;
      }
    }

  // mirror write for the off-diagonal tile via padded LDS transpose
  if (ti != tj) {
    float* tb = (float*)lds;  // [64][257] f32 = 65.8 KiB (reuses main LDS)
    for (int ch = 0; ch < 4; ++ch) {
      __syncthreads();
      if (wm == (ch >> 1)) {
        int i0 = (ch & 1) * 4;
#pragma unroll
        for (int i2 = 0; i2 < 4; i2++)
#pragma unroll
          for (int j = 0; j < 4; j++)
#pragma unroll
            for (int r = 0; r < 4; r++)
              tb[(i2 * 16 + kc * 4 + r) * 257 + wn * 64 + j * 16 + fr] =
                  acc[i0 + i2][j][r];
      }
      __syncthreads();
      for (int p = 0; p < 8; ++p) {
        int dl = p * 32 + (t >> 4);     // [0,256)
        int cl = (t & 15) * 4;          // [0,64)
        int dg = dblk + dl;
        float ud = ub[dg], rbd = rbb[dg];
        float4 o;
        float* op = (float*)&o;
#pragma unroll
        for (int q = 0; q < 4; ++q) {
          int cg = cblk + ch * 64 + cl + q;
          float raw = tb[(cl + q) * 257 + dl];
          op[q] = raw * invM - (ub[cg] * ud + rbb[cg] * rbd) * invM2;
        }
        *(float4*)&out[((size_t)b * C_N + dg) * C_N + (cblk + ch * 64 + cl)] = o;
      }
    }
  }
#undef SRC_A
#undef SRC_B
#undef DST
#undef STG2
}

extern "C" void kernel_launch(void* const* d_in, const int* in_sizes, int n_in,
                              void* d_out, int out_size, void* d_ws, size_t ws_size,
                              hipStream_t stream) {
  const float* h32 = (const float*)d_in[0];
  const float* conv_w = (const float*)d_in[1];
  const float* conv_b = (const float*)d_in[2];
  char* OUT = (char*)d_out;   // 64 MiB output
  char* HIN = (char*)d_in[0]; // 128 MiB input; becomes W in-place

  char* SCR = OUT + (48ull << 20);
  float* rb0   = (float*)SCR;                   // 128 KiB
  float* pesum = (float*)(SCR + (128 << 10));   // 2 KiB
  float* gateF = (float*)(SCR + (192 << 10));   // 128 KiB
  float* peF   = (float*)(OUT + (49ull << 20)); // 2 MiB fp32 pe table

  bool ws_ok = (d_ws != nullptr) && (ws_size >= (size_t)(256 << 10));
  float* uX = ws_ok ? (float*)d_ws : (float*)(SCR + (512 << 10));

  k_pe<<<C_N, 1024, 0, stream>>>(peF, pesum);
  k_rs<<<16384, 256, 0, stream>>>(h32, rb0);
  k_gate<<<(B_N * C_N) / 256, 256, 0, stream>>>(conv_w, conv_b, rb0, pesum,
                                                uX, uX + B_N * C_N, gateF);
  k_x<<<B_N * C_N, 256, 0, stream>>>(h32, (unsigned short*)HIN, peF, gateF);

  if (ws_ok) {
    // 192 = 8 XCD x (8 batches x 3 triangle 256-tiles)
    k_cov8<<<192, 512, 0, stream>>>((const unsigned short*)HIN, uX,
                                    (float*)d_out, 0, 8);
  } else {
    k_cov8<<<96, 512, 0, stream>>>((const unsigned short*)HIN, uX,
                                   (float*)d_out, 0, 4);
    hipMemcpyAsync(HIN, uX, 256 << 10, hipMemcpyDeviceToDevice, stream);
    k_cov8<<<96, 512, 0, stream>>>((const unsigned short*)HIN, (const float*)HIN,
                                   (float*)d_out, 32, 4);
  }
}